// Round 1
// 334.914 us; speedup vs baseline: 1.0896x; 1.0896x over previous
//
#include <hip/hip_runtime.h>

// ---------------------------------------------------------------------------
// Attention_20117626815094: c_t[b,t,d] = sum_e softmax_t(enc@dec^T)[e,t] * enc[e,d]
//   B=8, S_ENC=2048, S_DEC=2048, D=1024, fp32 in/out. f16 MFMA compute.
// Pipeline (v4 — 256^2 8-phase GEMMs, counted vmcnt):
//   1. conv_enc:  enc fp32 -> enc_h [e][d] f16 AND enc_hT [d][e] f16
//   2. conv_dec:  dec fp32 -> dec_h [t][d] f16
//   3. gemm8p:    ST[t][e] = dec_h @ enc_h^T  (direct, no transpose epilogue)
//   4. col_stats: online softmax over t per (b,e) column -> partials
//   5. stats_combine: merge t-chunk partials -> stats[b][e] = (m, 1/sum)
//   6. norm_stream: P[t][e] = exp(ST-m_e)*rl_e
//   7. gemm8p:    out[t][d] = P @ enc_hT^T-form (fp32 out)
// ---------------------------------------------------------------------------

typedef _Float16 half8 __attribute__((ext_vector_type(8)));
typedef _Float16 half4v __attribute__((ext_vector_type(4)));
typedef float floatx4 __attribute__((ext_vector_type(4)));

__device__ __forceinline__ void async_load16(const _Float16* g, void* l) {
  __builtin_amdgcn_global_load_lds(
      (const __attribute__((address_space(1))) void*)g,
      (__attribute__((address_space(3))) void*)l, 16, 0, 0);
}

// ---- 256x256 8-phase pipelined GEMM: C = A @ Bt^T --------------------------
// A[M][K], Bt[N][K] row-major f16, k contiguous. C row-major OutT.
// 512 threads = 8 waves (2m x 4n); per-wave 128x64 out; BK=64; LDS 128 KiB:
//   A slots [buf][half] 4x16K at 0; B slots at 64K. half = 128 rows x 64 k.
// Phases = C-quadrants (0,0)(0,1)(1,1)(1,0); b0 frags live P1->P4 so B slots
// free after P2, A slots after P3; next tile staged at P3 (B) / P4 (A);
// vmcnt(8) counted at each group end (next tile's 8 loads stay in flight).
template <typename OutT>
__global__ __launch_bounds__(512, 2) void gemm8p(
    const _Float16* __restrict__ A, const _Float16* __restrict__ Bt,
    OutT* __restrict__ C, int K, long strideA, long strideB, long strideC,
    int ldA, int ldB, int ldC) {
  extern __shared__ char smem_[];
  const int tid = threadIdx.x;
  const int lane = tid & 63;
  const int wave = tid >> 6;
  const int wm = wave >> 2;  // 0..1
  const int wn = wave & 3;   // 0..3
  const int l15 = lane & 15;
  const int lh = lane >> 4;  // 0..3

  // XCD swizzle over the flat grid (nwg % 8 == 0): XCD k gets a contiguous
  // chunk of tiles (= one batch for our shapes -> A/B panels stay in its L2).
  const int gx = gridDim.x, gxy = gridDim.x * gridDim.y;
  int fid = blockIdx.z * gxy + blockIdx.y * gx + blockIdx.x;
  const int nwg = gxy * gridDim.z;
  fid = (fid & 7) * (nwg >> 3) + (fid >> 3);
  const int b = fid / gxy;
  const int rem = fid - b * gxy;
  const int m0 = (rem / gx) * 256;
  const int n0 = (rem % gx) * 256;

  A += (long)b * strideA + (long)m0 * ldA;
  Bt += (long)b * strideB + (long)n0 * ldB;
  C += (long)b * strideC;

  floatx4 acc[8][4] = {};
  half8 a[4][2], b0[2][2], b1[2][2];

  // stage a full 256-row tile (A or B) into slot..slot+32K; XOR-swizzled src
  auto stage = [&](const _Float16* g, int ld, int k0, char* slot) {
#pragma unroll
    for (int i = 0; i < 4; ++i) {
      const int off = i * 8192 + tid * 16;  // lds dest: wave-uniform + lane*16
      const int row = off >> 7;             // 128 B per row
      const int ck = (off >> 4) & 7;
      async_load16(g + (long)row * ld + k0 + ((ck ^ (row & 7)) << 3),
                   slot + off);
    }
  };
  // read one mfma input frag (b128): row in slot, k-chunk = s*4+lh, swizzled
  auto ldf = [&](const char* slot, int row, int s) -> half8 {
    const int ck = (s * 4 + lh) ^ (row & 7);
    return *(const half8*)(slot + row * 128 + ck * 16);
  };
  auto mm = [&](int mh, int nh, half8(&bb)[2][2]) {
#pragma unroll
    for (int s = 0; s < 2; ++s)
#pragma unroll
      for (int q = 0; q < 4; ++q)
#pragma unroll
        for (int n = 0; n < 2; ++n)
          acc[mh * 4 + q][nh * 2 + n] = __builtin_amdgcn_mfma_f32_16x16x32_f16(
              a[q][s], bb[n][s], acc[mh * 4 + q][nh * 2 + n], 0, 0, 0);
  };
  auto barrier_ = [&]() {  // raw barrier, no vmcnt drain; fence load motion
    __builtin_amdgcn_sched_barrier(0);
    asm volatile("" ::: "memory");
    __builtin_amdgcn_s_barrier();
    asm volatile("" ::: "memory");
    __builtin_amdgcn_sched_barrier(0);
  };
  auto lgkm0_ = [&]() {
    asm volatile("s_waitcnt lgkmcnt(0)" ::: "memory");
    __builtin_amdgcn_sched_barrier(0);
  };

  auto quad4 = [&](int cur, int kst, int vmn) {
    const char* as_ = smem_ + cur * 32768 + wm * 16384;
    const char* bs_ = smem_ + 65536 + cur * 32768 + (wn >> 1) * 16384;
    const int brow = (wn & 1) * 64;
    // P1: quadrant (0,0) — 12 ds_read_b128
#pragma unroll
    for (int q = 0; q < 4; ++q)
#pragma unroll
      for (int s = 0; s < 2; ++s) a[q][s] = ldf(as_, q * 16 + l15, s);
#pragma unroll
    for (int n = 0; n < 2; ++n)
#pragma unroll
      for (int s = 0; s < 2; ++s) b0[n][s] = ldf(bs_, brow + n * 16 + l15, s);
    barrier_();
    lgkm0_();
    __builtin_amdgcn_s_setprio(1);
    mm(0, 0, b0);
    __builtin_amdgcn_s_setprio(0);
    barrier_();
    // P2: (0,1) — 4 ds_read
#pragma unroll
    for (int n = 0; n < 2; ++n)
#pragma unroll
      for (int s = 0; s < 2; ++s)
        b1[n][s] = ldf(bs_, brow + (n + 2) * 16 + l15, s);
    barrier_();
    lgkm0_();
    __builtin_amdgcn_s_setprio(1);
    mm(0, 1, b1);
    __builtin_amdgcn_s_setprio(0);
    barrier_();
    // P3: (1,1) — 8 ds_read; stage next B into this buf (B slots free: P2)
#pragma unroll
    for (int q = 0; q < 4; ++q)
#pragma unroll
      for (int s = 0; s < 2; ++s) a[q][s] = ldf(as_, (q + 4) * 16 + l15, s);
    if (kst >= 0) stage(Bt, ldB, kst, smem_ + 65536 + cur * 32768);
    barrier_();
    lgkm0_();
    __builtin_amdgcn_s_setprio(1);
    mm(1, 1, b1);
    __builtin_amdgcn_s_setprio(0);
    barrier_();
    // P4: (1,0) — reuses b0 regs; stage next A (A slots free: P3); vmcnt
    if (kst >= 0) stage(A, ldA, kst, smem_ + cur * 32768);
    barrier_();
    lgkm0_();
    __builtin_amdgcn_s_setprio(1);
    mm(1, 0, b0);
    __builtin_amdgcn_s_setprio(0);
    if (vmn)
      asm volatile("s_waitcnt vmcnt(8)" ::: "memory");
    else
      asm volatile("s_waitcnt vmcnt(0)" ::: "memory");
    __builtin_amdgcn_sched_barrier(0);
    barrier_();
  };

  // prologue: tiles 0 (buf0) and 1 (buf1); drain tile0's 8, keep tile1 in flight
  stage(A, ldA, 0, smem_);
  stage(Bt, ldB, 0, smem_ + 65536);
  stage(A, ldA, 64, smem_ + 32768);
  stage(Bt, ldB, 64, smem_ + 65536 + 32768);
  asm volatile("s_waitcnt vmcnt(8)" ::: "memory");
  barrier_();

  const int NT = K >> 6;
  for (int i = 0; i < (NT >> 1) - 1; ++i) {
    quad4(0, (2 * i + 2) * 64, 1);
    quad4(1, (2 * i + 3) * 64, 1);
  }
  quad4(0, -1, 0);  // vmcnt(0): last tile must land before reading buf1
  quad4(1, -1, 0);

  // C/D layout (verified): col=lane&15, row=(lane>>4)*4+reg
#pragma unroll
  for (int mf = 0; mf < 8; ++mf) {
    const long r0 = (long)(m0 + wm * 128 + mf * 16 + lh * 4);
#pragma unroll
    for (int nf = 0; nf < 4; ++nf) {
      const int cc = n0 + wn * 64 + nf * 16 + l15;
#pragma unroll
      for (int rr = 0; rr < 4; ++rr)
        C[(r0 + rr) * ldC + cc] = (OutT)acc[mf][nf][rr];
    }
  }
}

// ---- enc convert + transpose (4x4 register micro-transpose) ---------------
__global__ __launch_bounds__(256) void conv_enc(const float* __restrict__ E,
                                                _Float16* __restrict__ Eh,
                                                _Float16* __restrict__ EhT,
                                                int Se, int D) {
  __shared__ _Float16 T[64][72];
  const int b = blockIdx.z;
  const int d0 = blockIdx.x * 64;
  const int e0 = blockIdx.y * 64;
  const float* Eb = E + (size_t)b * Se * D;
  _Float16* Ehb = Eh + (size_t)b * Se * D;
  _Float16* EhTb = EhT + (size_t)b * D * Se;
  const int tid = threadIdx.x;
  const int tx = tid & 15;
  const int ty = tid >> 4;

  half4v h[4];
#pragma unroll
  for (int r = 0; r < 4; ++r) {
    const int e = e0 + ty * 4 + r;
    float4 v = *(const float4*)(Eb + (size_t)e * D + d0 + tx * 4);
    h[r][0] = (_Float16)v.x; h[r][1] = (_Float16)v.y;
    h[r][2] = (_Float16)v.z; h[r][3] = (_Float16)v.w;
    *(half4v*)(Ehb + (size_t)e * D + d0 + tx * 4) = h[r];
  }
#pragma unroll
  for (int c = 0; c < 4; ++c) {
    half4v w;
#pragma unroll
    for (int r = 0; r < 4; ++r) w[r] = h[r][c];
    *(half4v*)&T[tx * 4 + c][ty * 4] = w;
  }
  __syncthreads();
#pragma unroll
  for (int p = 0; p < 2; ++p) {
    const int idx = tid + p * 256;
    const int row = idx >> 3;
    const int ck = idx & 7;
    *(half8*)(EhTb + (size_t)(d0 + row) * Se + e0 + ck * 8) =
        *(const half8*)&T[row][ck * 8];
  }
}

// ---- dec convert (16B stores) ---------------------------------------------
__global__ __launch_bounds__(256) void conv_dec(const float* __restrict__ X,
                                                _Float16* __restrict__ Y) {
  const size_t i = ((size_t)blockIdx.x * 256 + threadIdx.x) * 8;
  float4 a = *(const float4*)(X + i);
  float4 b = *(const float4*)(X + i + 4);
  half8 h;
  h[0] = (_Float16)a.x; h[1] = (_Float16)a.y;
  h[2] = (_Float16)a.z; h[3] = (_Float16)a.w;
  h[4] = (_Float16)b.x; h[5] = (_Float16)b.y;
  h[6] = (_Float16)b.z; h[7] = (_Float16)b.w;
  *(half8*)(Y + i) = h;
}

// ---- column-wise online softmax stats over ST[t][e] -----------------------
// grid: (e_chunks=32, t_chunks=4, B); block 256. Each block: 64 e x 512 t.
__global__ __launch_bounds__(256) void col_stats(const _Float16* __restrict__ ST,
                                                 float2* __restrict__ part) {
  __shared__ float2 red[16][65];
  const int b = blockIdx.z;
  const int e0 = blockIdx.x * 64;
  const int t0 = blockIdx.y * 512;
  const _Float16* S = ST + (size_t)b * 2048 * 2048;
  const int tx = threadIdx.x & 15;
  const int ty = threadIdx.x >> 4;

  float m[4] = {-1e30f, -1e30f, -1e30f, -1e30f};
  float s[4] = {0.f, 0.f, 0.f, 0.f};
  for (int it = 0; it < 32; ++it) {
    const int t = t0 + it * 16 + ty;
    half4v v = *(const half4v*)(S + (size_t)t * 2048 + e0 + tx * 4);
#pragma unroll
    for (int c = 0; c < 4; ++c) {
      const float x = (float)v[c];
      const float m2 = fmaxf(m[c], x);
      s[c] = s[c] * __expf(m[c] - m2) + __expf(x - m2);
      m[c] = m2;
    }
  }
#pragma unroll
  for (int c = 0; c < 4; ++c) red[ty][tx * 4 + c] = make_float2(m[c], s[c]);
  __syncthreads();
  if (threadIdx.x < 64) {
    float2 a = red[0][threadIdx.x];
#pragma unroll
    for (int r = 1; r < 16; ++r) {
      const float2 o = red[r][threadIdx.x];
      const float m2 = fmaxf(a.x, o.x);
      a.y = a.y * __expf(a.x - m2) + o.y * __expf(o.x - m2);
      a.x = m2;
    }
    part[(size_t)blockIdx.y * 16384 + (size_t)b * 2048 + e0 + threadIdx.x] = a;
  }
}

// ---- merge 4 t-chunk partials -> stats = (m, 1/sum) -----------------------
__global__ __launch_bounds__(256) void stats_combine(
    const float2* __restrict__ part, float2* __restrict__ stats) {
  const int idx = blockIdx.x * 256 + threadIdx.x;  // b*2048+e
  float2 a = part[idx];
#pragma unroll
  for (int tc = 1; tc < 4; ++tc) {
    const float2 o = part[tc * 16384 + idx];
    const float m2 = fmaxf(a.x, o.x);
    a.y = a.y * __expf(a.x - m2) + o.y * __expf(o.x - m2);
    a.x = m2;
  }
  stats[idx] = make_float2(a.x, 1.0f / a.y);
}

// ---- streaming normalize: P[t][e] = exp(ST-m_e)*rl_e ----------------------
// grid: (512, 8); block 256; 4 t-rows per block, stats reused across rows.
__global__ __launch_bounds__(256) void norm_stream(
    const _Float16* __restrict__ ST, const float2* __restrict__ stats,
    _Float16* __restrict__ P) {
  const int b = blockIdx.y;
  const int t0 = blockIdx.x * 4;
  const int e = threadIdx.x * 8;
  float m_[8], rl_[8];
#pragma unroll
  for (int j = 0; j < 8; ++j) {
    const float2 st = stats[(size_t)b * 2048 + e + j];
    m_[j] = st.x;
    rl_[j] = st.y;
  }
  const size_t base = ((size_t)b * 2048 + t0) * 2048 + e;
#pragma unroll
  for (int r = 0; r < 4; ++r) {
    half8 v = *(const half8*)(ST + base + (size_t)r * 2048);
    half8 o;
#pragma unroll
    for (int j = 0; j < 8; ++j)
      o[j] = (_Float16)(__expf((float)v[j] - m_[j]) * rl_[j]);
    *(half8*)(P + base + (size_t)r * 2048) = o;
  }
}

// ---------------------------------------------------------------------------
extern "C" void kernel_launch(void* const* d_in, const int* in_sizes, int n_in,
                              void* d_out, int out_size, void* d_ws,
                              size_t ws_size, hipStream_t stream) {
  const float* enc = (const float*)d_in[0];
  const float* dec = (const float*)d_in[1];
  float* out = (float*)d_out;

  const int B = 8, SE = 2048, SD = 2048, D = 1024;
  char* ws = (char*)d_ws;
  _Float16* enc_h = (_Float16*)ws;                 // 32 MiB (dead after gemm1)
  _Float16* dec_h = (_Float16*)(ws + 33554432);    // 32 MiB (dead after gemm1)
  _Float16* P = (_Float16*)ws;                     // 64 MiB (reuses enc/dec_h)
  _Float16* enc_hT = (_Float16*)(ws + 67108864);   // 32 MiB
  _Float16* ST = (_Float16*)(ws + 100663296);      // 64 MiB
  float2* stats = (float2*)(ws + 167772160);       // 128 KiB
  float2* part = (float2*)(ws + 167903232);        // 512 KiB

  static int smem_set = 0;
  if (!smem_set) {
    (void)hipFuncSetAttribute(
        reinterpret_cast<const void*>(&gemm8p<_Float16>),
        hipFuncAttributeMaxDynamicSharedMemorySize, 131072);
    (void)hipFuncSetAttribute(
        reinterpret_cast<const void*>(&gemm8p<float>),
        hipFuncAttributeMaxDynamicSharedMemorySize, 131072);
    smem_set = 1;
  }

  conv_enc<<<dim3(D / 64, SE / 64, B), 256, 0, stream>>>(enc, enc_h, enc_hT,
                                                         SE, D);
  conv_dec<<<dim3((size_t)B * SD * D / 2048), 256, 0, stream>>>(dec, dec_h);
  // ST[t][e] = dec_h @ enc_h^T  (M=t, N=e, K=D) — direct, no transpose
  gemm8p<_Float16><<<dim3(SE / 256, SD / 256, B), 512, 131072, stream>>>(
      dec_h, enc_h, ST, D, (long)SD * D, (long)SE * D, (long)SD * SE, D, D,
      SE);
  col_stats<<<dim3(32, 4, B), 256, 0, stream>>>(ST, part);
  stats_combine<<<dim3(64), 256, 0, stream>>>(part, stats);
  norm_stream<<<dim3(512, B), 256, 0, stream>>>(ST, stats, P);
  // out[t][d] = P @ enc_hT^T-form  (M=t, N=d, K=e)
  gemm8p<float><<<dim3(D / 256, SD / 256, B), 512, 131072, stream>>>(
      P, enc_hT, out, SE, (long)SD * SE, (long)D * SE, (long)SD * D, SE, SE,
      D);
}

// Round 3
// 332.008 us; speedup vs baseline: 1.0991x; 1.0088x over previous
//
#include <hip/hip_runtime.h>

// ---------------------------------------------------------------------------
// Attention_20117626815094: c_t[b,t,d] = sum_e softmax_t(enc@dec^T)[e,t] * enc[e,d]
//   B=8, S_ENC=2048, S_DEC=2048, D=1024, fp32 in/out. f16 MFMA compute.
// Pipeline (v6 — 256^2 8-phase GEMMs, precomputed swizzled addrs, correct
// A-low/A-high liveness: A-high loaded only after mm(0,1) consumed A-low):
//   1. conv_enc:  enc fp32 -> enc_h [e][d] f16 AND enc_hT [d][e] f16
//   2. conv_dec:  dec fp32 -> dec_h [t][d] f16
//   3. gemm8p:    ST[t][e] = dec_h @ enc_h^T
//   4. col_stats: online softmax over t per (b,e) column -> partials
//   5. stats_combine: merge t-chunk partials -> stats[b][e] = (m, 1/sum)
//   6. norm_stream: P[t][e] = exp(ST-m_e)*rl_e
//   7. gemm8p:    out[t][d] = P @ enc_hT^T-form (fp32 out)
// ---------------------------------------------------------------------------

typedef _Float16 half8 __attribute__((ext_vector_type(8)));
typedef _Float16 half4v __attribute__((ext_vector_type(4)));
typedef float floatx4 __attribute__((ext_vector_type(4)));

__device__ __forceinline__ void async_load16(const _Float16* g, void* l) {
  __builtin_amdgcn_global_load_lds(
      (const __attribute__((address_space(1))) void*)g,
      (__attribute__((address_space(3))) void*)l, 16, 0, 0);
}

// ---- 256x256 8-phase pipelined GEMM: C = A @ Bt^T --------------------------
// A[M][K], Bt[N][K] row-major f16, k contiguous. C row-major OutT.
// 512 threads = 8 waves (2m x 4n); per-wave 128x64 out; BK=64; LDS 128 KiB.
// Swizzle: 16B chunk ck of row stored at ck^(row&7); row&7==l15&7 for all
// frag reads -> per-lane base lb0 (s=0) / lb1=lb0^64 (s=1), frag = +q*2048.
// Phases (quadrant order (0,0)(0,1)(1,1)(1,0); b0 regs live P1->P4):
//   P1: issue a-lo + b0 + b1 reads; mm(0,0)   [b1 early: separate regs]
//   P2: (no reads);                 mm(0,1)   [consumes a-lo, b1]
//   P3: issue a-hi; stage next B;   mm(1,1)   [B slot free after P2]
//   P4: stage next A;               mm(1,0); vmcnt(8)  [A slot free after P3]
// vmcnt counted (8 = next tile's loads stay in flight), never 0 in main loop.
template <typename OutT>
__global__ __launch_bounds__(512, 2) void gemm8p(
    const _Float16* __restrict__ A, const _Float16* __restrict__ Bt,
    OutT* __restrict__ C, int K, long strideA, long strideB, long strideC,
    int ldA, int ldB, int ldC) {
  extern __shared__ char smem_[];
  const int tid = threadIdx.x;
  const int lane = tid & 63;
  const int wave = tid >> 6;
  const int wm = wave >> 2;  // 0..1
  const int wn = wave & 3;   // 0..3
  const int l15 = lane & 15;
  const int lh = lane >> 4;  // 0..3

  // XCD swizzle over the flat grid (nwg % 8 == 0)
  const int gx = gridDim.x, gxy = gridDim.x * gridDim.y;
  int fid = blockIdx.z * gxy + blockIdx.y * gx + blockIdx.x;
  const int nwg = gxy * gridDim.z;
  fid = (fid & 7) * (nwg >> 3) + (fid >> 3);
  const int b = fid / gxy;
  const int rem = fid - b * gxy;
  const int m0 = (rem / gx) * 256;
  const int n0 = (rem % gx) * 256;

  A += (long)b * strideA + (long)m0 * ldA;
  Bt += (long)b * strideB + (long)n0 * ldB;
  C += (long)b * strideC;

  // precomputed swizzled LDS read bases
  const int lb0 = l15 * 128 + ((lh ^ (l15 & 7)) << 4);
  const int lb1 = lb0 ^ 64;
  const char* aBuf[2] = {smem_ + wm * 16384, smem_ + 32768 + wm * 16384};
  const char* bBuf[2] = {
      smem_ + 65536 + (wn >> 1) * 16384 + (wn & 1) * 8192,
      smem_ + 98304 + (wn >> 1) * 16384 + (wn & 1) * 8192};
  char* aSlot[2] = {smem_, smem_ + 32768};
  char* bSlot[2] = {smem_ + 65536, smem_ + 98304};

  // precomputed per-thread staging source bases (swizzle folded in)
  const int srow = tid >> 3;
  const int skk = ((tid & 7) ^ (srow & 7)) << 3;
  const _Float16* Ast = A + (long)srow * ldA + skk;
  const _Float16* Bst = Bt + (long)srow * ldB + skk;
  const int dst = tid << 4;

  floatx4 acc[8][4] = {};
  half8 a[4][2], b0[2][2], b1[2][2];

  auto stage = [&](const _Float16* gs, int ld, int k0, char* slot) {
#pragma unroll
    for (int i = 0; i < 4; ++i)
      async_load16(gs + (long)(i * 64) * ld + k0, slot + i * 8192 + dst);
  };
  auto mm = [&](int mh, int nh, half8(&bb)[2][2]) {
    __builtin_amdgcn_s_setprio(1);
#pragma unroll
    for (int s = 0; s < 2; ++s)
#pragma unroll
      for (int q = 0; q < 4; ++q)
#pragma unroll
        for (int n = 0; n < 2; ++n)
          acc[mh * 4 + q][nh * 2 + n] = __builtin_amdgcn_mfma_f32_16x16x32_f16(
              a[q][s], bb[n][s], acc[mh * 4 + q][nh * 2 + n], 0, 0, 0);
    __builtin_amdgcn_s_setprio(0);
  };
  auto bar = [&]() { asm volatile("s_barrier" ::: "memory"); };

  auto quad4 = [&](int cur, int kst, bool last) {
    const char* aB_ = aBuf[cur];
    const char* bB_ = bBuf[cur];
    // P1: issue A-low (q=0..3) and ALL B frag reads; compute (0,0)
#pragma unroll
    for (int q = 0; q < 4; ++q) {
      a[q][0] = *(const half8*)(aB_ + lb0 + q * 2048);
      a[q][1] = *(const half8*)(aB_ + lb1 + q * 2048);
    }
#pragma unroll
    for (int n = 0; n < 2; ++n) {
      b0[n][0] = *(const half8*)(bB_ + lb0 + n * 2048);
      b0[n][1] = *(const half8*)(bB_ + lb1 + n * 2048);
      b1[n][0] = *(const half8*)(bB_ + lb0 + (n + 2) * 2048);
      b1[n][1] = *(const half8*)(bB_ + lb1 + (n + 2) * 2048);
    }
    bar();
    mm(0, 0, b0);
    bar();
    // P2: no reads (b1 issued in P1; a-lo still live for mm(0,1))
    bar();
    mm(0, 1, b1);
    bar();
    // P3: issue A-high (a-lo dead after mm(0,1)); stage next-tile B
    //     (B slot fully consumed after P2); compute (1,1)
#pragma unroll
    for (int q = 0; q < 4; ++q) {
      a[q][0] = *(const half8*)(aB_ + lb0 + (q + 4) * 2048);
      a[q][1] = *(const half8*)(aB_ + lb1 + (q + 4) * 2048);
    }
    if (kst >= 0) stage(Bst, ldB, kst, bSlot[cur]);
    bar();
    mm(1, 1, b1);
    bar();
    // P4: stage next-tile A (A slot fully consumed after P3); compute (1,0)
    if (kst >= 0) stage(Ast, ldA, kst, aSlot[cur]);
    mm(1, 0, b0);
    if (last)
      asm volatile("s_waitcnt vmcnt(0)" ::: "memory");
    else
      asm volatile("s_waitcnt vmcnt(8)" ::: "memory");
    bar();
  };

  // prologue: tiles 0,1 -> bufs 0,1; drain tile0's 8, keep tile1 in flight
  stage(Ast, ldA, 0, aSlot[0]);
  stage(Bst, ldB, 0, bSlot[0]);
  stage(Ast, ldA, 64, aSlot[1]);
  stage(Bst, ldB, 64, bSlot[1]);
  asm volatile("s_waitcnt vmcnt(8)" ::: "memory");
  bar();

  const int NT = K >> 6;
  for (int i = 0; i < (NT >> 1) - 1; ++i) {
    quad4(0, (2 * i + 2) * 64, false);
    quad4(1, (2 * i + 3) * 64, false);
  }
  quad4(0, -1, true);  // vmcnt(0): last tile must land before reading buf1
  quad4(1, -1, true);

  // C/D layout (verified): col=lane&15, row=(lane>>4)*4+reg
#pragma unroll
  for (int mf = 0; mf < 8; ++mf) {
    const long r0 = (long)(m0 + wm * 128 + mf * 16 + lh * 4);
#pragma unroll
    for (int nf = 0; nf < 4; ++nf) {
      const int cc = n0 + wn * 64 + nf * 16 + l15;
#pragma unroll
      for (int rr = 0; rr < 4; ++rr)
        C[(r0 + rr) * ldC + cc] = (OutT)acc[mf][nf][rr];
    }
  }
}

// ---- enc convert + transpose (4x4 register micro-transpose) ---------------
__global__ __launch_bounds__(256) void conv_enc(const float* __restrict__ E,
                                                _Float16* __restrict__ Eh,
                                                _Float16* __restrict__ EhT,
                                                int Se, int D) {
  __shared__ _Float16 T[64][72];
  const int b = blockIdx.z;
  const int d0 = blockIdx.x * 64;
  const int e0 = blockIdx.y * 64;
  const float* Eb = E + (size_t)b * Se * D;
  _Float16* Ehb = Eh + (size_t)b * Se * D;
  _Float16* EhTb = EhT + (size_t)b * D * Se;
  const int tid = threadIdx.x;
  const int tx = tid & 15;
  const int ty = tid >> 4;

  half4v h[4];
#pragma unroll
  for (int r = 0; r < 4; ++r) {
    const int e = e0 + ty * 4 + r;
    float4 v = *(const float4*)(Eb + (size_t)e * D + d0 + tx * 4);
    h[r][0] = (_Float16)v.x; h[r][1] = (_Float16)v.y;
    h[r][2] = (_Float16)v.z; h[r][3] = (_Float16)v.w;
    *(half4v*)(Ehb + (size_t)e * D + d0 + tx * 4) = h[r];
  }
#pragma unroll
  for (int c = 0; c < 4; ++c) {
    half4v w;
#pragma unroll
    for (int r = 0; r < 4; ++r) w[r] = h[r][c];
    *(half4v*)&T[tx * 4 + c][ty * 4] = w;
  }
  __syncthreads();
#pragma unroll
  for (int p = 0; p < 2; ++p) {
    const int idx = tid + p * 256;
    const int row = idx >> 3;
    const int ck = idx & 7;
    *(half8*)(EhTb + (size_t)(d0 + row) * Se + e0 + ck * 8) =
        *(const half8*)&T[row][ck * 8];
  }
}

// ---- dec convert (16B stores) ---------------------------------------------
__global__ __launch_bounds__(256) void conv_dec(const float* __restrict__ X,
                                                _Float16* __restrict__ Y) {
  const size_t i = ((size_t)blockIdx.x * 256 + threadIdx.x) * 8;
  float4 a = *(const float4*)(X + i);
  float4 b = *(const float4*)(X + i + 4);
  half8 h;
  h[0] = (_Float16)a.x; h[1] = (_Float16)a.y;
  h[2] = (_Float16)a.z; h[3] = (_Float16)a.w;
  h[4] = (_Float16)b.x; h[5] = (_Float16)b.y;
  h[6] = (_Float16)b.z; h[7] = (_Float16)b.w;
  *(half8*)(Y + i) = h;
}

// ---- column-wise online softmax stats over ST[t][e] -----------------------
// grid: (e_chunks=32, t_chunks=4, B); block 256. Each block: 64 e x 512 t.
__global__ __launch_bounds__(256) void col_stats(const _Float16* __restrict__ ST,
                                                 float2* __restrict__ part) {
  __shared__ float2 red[16][65];
  const int b = blockIdx.z;
  const int e0 = blockIdx.x * 64;
  const int t0 = blockIdx.y * 512;
  const _Float16* S = ST + (size_t)b * 2048 * 2048;
  const int tx = threadIdx.x & 15;
  const int ty = threadIdx.x >> 4;

  float m[4] = {-1e30f, -1e30f, -1e30f, -1e30f};
  float s[4] = {0.f, 0.f, 0.f, 0.f};
  for (int it = 0; it < 32; ++it) {
    const int t = t0 + it * 16 + ty;
    half4v v = *(const half4v*)(S + (size_t)t * 2048 + e0 + tx * 4);
#pragma unroll
    for (int c = 0; c < 4; ++c) {
      const float x = (float)v[c];
      const float m2 = fmaxf(m[c], x);
      s[c] = s[c] * __expf(m[c] - m2) + __expf(x - m2);
      m[c] = m2;
    }
  }
#pragma unroll
  for (int c = 0; c < 4; ++c) red[ty][tx * 4 + c] = make_float2(m[c], s[c]);
  __syncthreads();
  if (threadIdx.x < 64) {
    float2 a = red[0][threadIdx.x];
#pragma unroll
    for (int r = 1; r < 16; ++r) {
      const float2 o = red[r][threadIdx.x];
      const float m2 = fmaxf(a.x, o.x);
      a.y = a.y * __expf(a.x - m2) + o.y * __expf(o.x - m2);
      a.x = m2;
    }
    part[(size_t)blockIdx.y * 16384 + (size_t)b * 2048 + e0 + threadIdx.x] = a;
  }
}

// ---- merge 4 t-chunk partials -> stats = (m, 1/sum) -----------------------
__global__ __launch_bounds__(256) void stats_combine(
    const float2* __restrict__ part, float2* __restrict__ stats) {
  const int idx = blockIdx.x * 256 + threadIdx.x;  // b*2048+e
  float2 a = part[idx];
#pragma unroll
  for (int tc = 1; tc < 4; ++tc) {
    const float2 o = part[tc * 16384 + idx];
    const float m2 = fmaxf(a.x, o.x);
    a.y = a.y * __expf(a.x - m2) + o.y * __expf(o.x - m2);
    a.x = m2;
  }
  stats[idx] = make_float2(a.x, 1.0f / a.y);
}

// ---- streaming normalize: P[t][e] = exp(ST-m_e)*rl_e ----------------------
// grid: (512, 8); block 256; 4 t-rows per block, stats reused across rows.
__global__ __launch_bounds__(256) void norm_stream(
    const _Float16* __restrict__ ST, const float2* __restrict__ stats,
    _Float16* __restrict__ P) {
  const int b = blockIdx.y;
  const int t0 = blockIdx.x * 4;
  const int e = threadIdx.x * 8;
  float m_[8], rl_[8];
#pragma unroll
  for (int j = 0; j < 8; ++j) {
    const float2 st = stats[(size_t)b * 2048 + e + j];
    m_[j] = st.x;
    rl_[j] = st.y;
  }
  const size_t base = ((size_t)b * 2048 + t0) * 2048 + e;
#pragma unroll
  for (int r = 0; r < 4; ++r) {
    half8 v = *(const half8*)(ST + base + (size_t)r * 2048);
    half8 o;
#pragma unroll
    for (int j = 0; j < 8; ++j)
      o[j] = (_Float16)(__expf((float)v[j] - m_[j]) * rl_[j]);
    *(half8*)(P + base + (size_t)r * 2048) = o;
  }
}

// ---------------------------------------------------------------------------
extern "C" void kernel_launch(void* const* d_in, const int* in_sizes, int n_in,
                              void* d_out, int out_size, void* d_ws,
                              size_t ws_size, hipStream_t stream) {
  const float* enc = (const float*)d_in[0];
  const float* dec = (const float*)d_in[1];
  float* out = (float*)d_out;

  const int B = 8, SE = 2048, SD = 2048, D = 1024;
  char* ws = (char*)d_ws;
  _Float16* enc_h = (_Float16*)ws;                 // 32 MiB (dead after gemm1)
  _Float16* dec_h = (_Float16*)(ws + 33554432);    // 32 MiB (dead after gemm1)
  _Float16* P = (_Float16*)ws;                     // 64 MiB (reuses enc/dec_h)
  _Float16* enc_hT = (_Float16*)(ws + 67108864);   // 32 MiB
  _Float16* ST = (_Float16*)(ws + 100663296);      // 64 MiB
  float2* stats = (float2*)(ws + 167772160);       // 128 KiB
  float2* part = (float2*)(ws + 167903232);        // 512 KiB

  static int smem_set = 0;
  if (!smem_set) {
    (void)hipFuncSetAttribute(
        reinterpret_cast<const void*>(&gemm8p<_Float16>),
        hipFuncAttributeMaxDynamicSharedMemorySize, 131072);
    (void)hipFuncSetAttribute(
        reinterpret_cast<const void*>(&gemm8p<float>),
        hipFuncAttributeMaxDynamicSharedMemorySize, 131072);
    smem_set = 1;
  }

  conv_enc<<<dim3(D / 64, SE / 64, B), 256, 0, stream>>>(enc, enc_h, enc_hT,
                                                         SE, D);
  conv_dec<<<dim3((size_t)B * SD * D / 2048), 256, 0, stream>>>(dec, dec_h);
  // ST[t][e] = dec_h @ enc_h^T  (M=t, N=e, K=D)
  gemm8p<_Float16><<<dim3(SE / 256, SD / 256, B), 512, 131072, stream>>>(
      dec_h, enc_h, ST, D, (long)SD * D, (long)SE * D, (long)SD * SE, D, D,
      SE);
  col_stats<<<dim3(32, 4, B), 256, 0, stream>>>(ST, part);
  stats_combine<<<dim3(64), 256, 0, stream>>>(part, stats);
  norm_stream<<<dim3(512, B), 256, 0, stream>>>(ST, stats, P);
  // out[t][d] = P @ enc_hT^T-form  (M=t, N=d, K=e)
  gemm8p<float><<<dim3(D / 256, SD / 256, B), 512, 131072, stream>>>(
      P, enc_hT, out, SE, (long)SD * SE, (long)D * SE, (long)SD * D, SE, SE,
      D);
}